// Round 3
// baseline (513.059 us; speedup 1.0000x reference)
//
#include <hip/hip_runtime.h>
#include <stdint.h>

typedef __attribute__((ext_vector_type(8))) short s16x8;
typedef __attribute__((ext_vector_type(4))) float f32x4;

__device__ __forceinline__ unsigned short f2bf(float f) {
  unsigned int u = __float_as_uint(f);
  u += 0x7fffu + ((u >> 16) & 1u);
  return (unsigned short)(u >> 16);
}
__device__ __forceinline__ float bf2f(unsigned short h) {
  return __uint_as_float(((unsigned int)h) << 16);
}
__device__ __forceinline__ f32x4 mfma16(s16x8 a, s16x8 b, f32x4 c) {
  return __builtin_amdgcn_mfma_f32_16x16x32_bf16(a, b, c, 0, 0, 0);
}

// ---------------- attention kernel: one block per batch ----------------
// LDS plan (union), 40960 B total -> 4 blocks/CU (4*40960 = 163840 = full LDS):
//  phase 1/2 (S = Q K^T):  Kh[64][136] @0 (17408 B), Kl[64][136] @17408 -> 34816 B
//  phase 3  (A = P V):     Vt[256][64] @0 swizzled (32768 B),
//                          P[64][64]   @32768 swizzled (8192 B)        -> 40960 B
// Swizzle (G4): rows are 128 B = 32 dwords; unpadded stride would put all
// row-sliced b128 reads in one bank. byte ^= (row&7)<<4 on BOTH write and read
// (same involution both sides) spreads the 8 16B-slots across row-classes.
#define KH_STR 136

__device__ __forceinline__ int swz128(int row, int byteoff) {
  return row * 128 + (byteoff ^ ((row & 7) << 4));
}

__global__ __launch_bounds__(256) void attn_kernel(
    const float* __restrict__ Vg, const float* __restrict__ Kg,
    const float* __restrict__ Qg, float* __restrict__ attn_out,
    unsigned short* __restrict__ xb /* bf16 x = attn+q, may be null */) {
  __shared__ __align__(16) char smem[40960];
  unsigned short* KhL = (unsigned short*)smem;
  unsigned short* KlL = (unsigned short*)(smem + 17408);
  char* VtB = smem;            // swizzled Vt[256][64] bf16
  char* PB  = smem + 32768;    // swizzled P[64][64] bf16

  const int b = blockIdx.x;
  const int tid = threadIdx.x;
  const int lane = tid & 63;
  const int w = tid >> 6;       // wave id: owns S/A rows 16w..16w+15
  const int n = lane & 15;
  const int q = lane >> 4;

  const float* Qb = Qg + (size_t)b * 64 * 256;
  const float* Kb = Kg + (size_t)b * 64 * 256;
  const float* Vb = Vg + (size_t)b * 64 * 256;

  f32x4 accS[4];
#pragma unroll
  for (int c = 0; c < 4; ++c) accS[c] = f32x4{0.f, 0.f, 0.f, 0.f};

  // ---- S = Q K^T, hi/lo bf16 split, two 128-wide e-chunks ----
  for (int ph = 0; ph < 2; ++ph) {
    const int e0 = ph * 128;
    // stage K chunk 64x128 fp32 -> hi/lo bf16 LDS
#pragma unroll
    for (int it = 0; it < 8; ++it) {
      int i = it * 256 + tid;
      int row = i >> 5;
      int c4 = i & 31;
      float4 v = *(const float4*)(Kb + row * 256 + e0 + c4 * 4);
      ushort4 hi, lo;
      hi.x = f2bf(v.x); lo.x = f2bf(v.x - bf2f(hi.x));
      hi.y = f2bf(v.y); lo.y = f2bf(v.y - bf2f(hi.y));
      hi.z = f2bf(v.z); lo.z = f2bf(v.z - bf2f(hi.z));
      hi.w = f2bf(v.w); lo.w = f2bf(v.w - bf2f(hi.w));
      *(ushort4*)(KhL + row * KH_STR + c4 * 4) = hi;
      *(ushort4*)(KlL + row * KH_STR + c4 * 4) = lo;
    }
    __syncthreads();
#pragma unroll
    for (int kk = 0; kk < 4; ++kk) {
      const float* qsrc = Qb + (16 * w + n) * 256 + e0 + kk * 32 + q * 8;
      float4 a0 = *(const float4*)qsrc;
      float4 a1 = *(const float4*)(qsrc + 4);
      float av[8] = {a0.x, a0.y, a0.z, a0.w, a1.x, a1.y, a1.z, a1.w};
      s16x8 qh, ql;
#pragma unroll
      for (int j = 0; j < 8; ++j) {
        unsigned short h = f2bf(av[j]);
        qh[j] = (short)h;
        ql[j] = (short)f2bf(av[j] - bf2f(h));
      }
      const int colb = kk * 32 + q * 8;
#pragma unroll
      for (int c = 0; c < 4; ++c) {
        s16x8 kh = *(const s16x8*)(KhL + (16 * c + n) * KH_STR + colb);
        s16x8 kl = *(const s16x8*)(KlL + (16 * c + n) * KH_STR + colb);
        accS[c] = mfma16(qh, kh, accS[c]);
        accS[c] = mfma16(qh, kl, accS[c]);
        accS[c] = mfma16(ql, kh, accS[c]);
      }
    }
    __syncthreads();  // before restaging / Vt overwrite
  }

  // ---- in-register softmax. lane holds S[16w+4q+r][16c+n] in accS[c][r] ----
  const float scale = 0.125f;
  float p[4][4];
#pragma unroll
  for (int r = 0; r < 4; ++r) {
    float m = -1e30f;
#pragma unroll
    for (int c = 0; c < 4; ++c) m = fmaxf(m, accS[c][r]);
#pragma unroll
    for (int mk = 1; mk < 16; mk <<= 1) m = fmaxf(m, __shfl_xor(m, mk, 64));
    float s = 0.f;
#pragma unroll
    for (int c = 0; c < 4; ++c) {
      float e = __expf((accS[c][r] - m) * scale);
      p[c][r] = e;
      s += e;
    }
#pragma unroll
    for (int mk = 1; mk < 16; mk <<= 1) s += __shfl_xor(s, mk, 64);
    float inv = 1.0f / s;
#pragma unroll
    for (int c = 0; c < 4; ++c) p[c][r] *= inv;
  }

  // ---- stage V^T (bf16, swizzled, b128 writes) and P (bf16, swizzled) ----
  // Thread owns Vt row e = tid; 8 groups of 8 t-values -> one ds_write_b128 each.
#pragma unroll
  for (int g = 0; g < 8; ++g) {
    s16x8 pk;
#pragma unroll
    for (int j = 0; j < 8; ++j) pk[j] = (short)f2bf(Vb[(8 * g + j) * 256 + tid]);
    *(s16x8*)(VtB + swz128(tid, 16 * g)) = pk;
  }
#pragma unroll
  for (int r = 0; r < 4; ++r) {
    int row = 16 * w + 4 * q + r;
#pragma unroll
    for (int c = 0; c < 4; ++c)
      *(unsigned short*)(PB + swz128(row, 2 * (16 * c + n))) = f2bf(p[c][r]);
  }
  __syncthreads();

  // ---- A = P V via MFMA, wave w does rows 16w..16w+15, all 256 cols ----
  f32x4 accA[16];
#pragma unroll
  for (int c = 0; c < 16; ++c) accA[c] = f32x4{0.f, 0.f, 0.f, 0.f};
#pragma unroll
  for (int ks = 0; ks < 2; ++ks) {
    const int colb = ks * 32 + q * 8;
    s16x8 af = *(const s16x8*)(PB + swz128(16 * w + n, 2 * colb));
#pragma unroll
    for (int c = 0; c < 16; ++c) {
      s16x8 bf = *(const s16x8*)(VtB + swz128(16 * c + n, 2 * colb));
      accA[c] = mfma16(af, bf, accA[c]);
    }
  }

  // ---- epilogue: attention (fp32) and x = attention + query (bf16) ----
#pragma unroll
  for (int r = 0; r < 4; ++r) {
    int t = 16 * w + 4 * q + r;
    size_t base = ((size_t)b * 64 + t) * 256;
#pragma unroll
    for (int c = 0; c < 16; ++c) {
      int e = 16 * c + n;
      float aval = accA[c][r];
      attn_out[base + e] = aval;
      if (xb) xb[base + e] = f2bf(aval + Qb[t * 256 + e]);
    }
  }
}

// ---------------- W_ff fp32 -> bf16 ----------------
__global__ __launch_bounds__(256) void w2b_kernel(const float* __restrict__ W,
                                                  unsigned short* __restrict__ Wb) {
  int i = blockIdx.x * 256 + threadIdx.x;  // one float4 each, grid covers exactly
  float4 v = ((const float4*)W)[i];
  ushort4 o;
  o.x = f2bf(v.x); o.y = f2bf(v.y); o.z = f2bf(v.z); o.w = f2bf(v.w);
  ((ushort4*)Wb)[i] = o;
}

// ---------------- FF GEMM: out_part = x @ W^T, 64x64 tiles, K-split ----------------
// (byte-identical to round 2: KS=16 -> 2048 blocks -> 8 blocks/CU)
template <bool USE_XB>
__global__ __launch_bounds__(256) void ff_kernel(
    const unsigned short* __restrict__ xb, const float* __restrict__ attn,
    const float* __restrict__ query, const unsigned short* __restrict__ Wb,
    float* __restrict__ part, int kchunk) {
  __shared__ __align__(16) unsigned short As[64 * 72];
  __shared__ __align__(16) unsigned short Bs[64 * 72];
  const int tid = threadIdx.x;
  const int lane = tid & 63, w = tid >> 6, n = lane & 15, q = lane >> 4;
  const int m0 = blockIdx.x * 64;
  const int n0 = blockIdx.y * 64;
  const int k0 = blockIdx.z * kchunk;

  f32x4 acc[4];
#pragma unroll
  for (int c = 0; c < 4; ++c) acc[c] = f32x4{0.f, 0.f, 0.f, 0.f};

  const int srow = tid >> 3;  // 0..31
  const int scol = (tid & 7) * 8;

  for (int kk = 0; kk < kchunk; kk += 64) {
#pragma unroll
    for (int rr = 0; rr < 2; ++rr) {
      int row = rr * 32 + srow;
      size_t ga = (size_t)(m0 + row) * 16384 + k0 + kk + scol;
      if (USE_XB) {
        *(uint4*)(As + row * 72 + scol) = *(const uint4*)(xb + ga);
      } else {
        float4 a0 = *(const float4*)(attn + ga);
        float4 a1 = *(const float4*)(attn + ga + 4);
        float4 q0 = *(const float4*)(query + ga);
        float4 q1 = *(const float4*)(query + ga + 4);
        ushort4 h0, h1;
        h0.x = f2bf(a0.x + q0.x); h0.y = f2bf(a0.y + q0.y);
        h0.z = f2bf(a0.z + q0.z); h0.w = f2bf(a0.w + q0.w);
        h1.x = f2bf(a1.x + q1.x); h1.y = f2bf(a1.y + q1.y);
        h1.z = f2bf(a1.z + q1.z); h1.w = f2bf(a1.w + q1.w);
        *(ushort4*)(As + row * 72 + scol) = h0;
        *(ushort4*)(As + row * 72 + scol + 4) = h1;
      }
      size_t gw = (size_t)(n0 + row) * 16384 + k0 + kk + scol;
      *(uint4*)(Bs + row * 72 + scol) = *(const uint4*)(Wb + gw);
    }
    __syncthreads();
#pragma unroll
    for (int ks = 0; ks < 2; ++ks) {
      const int colb = ks * 32 + q * 8;
      s16x8 af = *(const s16x8*)(As + (16 * w + n) * 72 + colb);
#pragma unroll
      for (int c = 0; c < 4; ++c) {
        s16x8 bf = *(const s16x8*)(Bs + (16 * c + n) * 72 + colb);
        acc[c] = mfma16(af, bf, acc[c]);
      }
    }
    __syncthreads();
  }
#pragma unroll
  for (int r = 0; r < 4; ++r) {
    int m = m0 + 16 * w + 4 * q + r;
#pragma unroll
    for (int c = 0; c < 4; ++c) {
      int nn = n0 + 16 * c + n;
      part[((size_t)blockIdx.z * 2048 + m) * 256 + nn] = acc[c][r];
    }
  }
}

// ---------------- reduce K-split partials + bias + ReLU (float4) ----------------
__global__ __launch_bounds__(256) void relu_kernel(const float* __restrict__ part,
                                                   const float* __restrict__ bias,
                                                   float* __restrict__ out, int KS) {
  int i4 = blockIdx.x * 256 + threadIdx.x;  // float4 index, 131072 total
  const float4* p4 = (const float4*)part;
  float4 s = ((const float4*)bias)[i4 & 63];
  for (int ks = 0; ks < KS; ++ks) {
    float4 v = p4[(size_t)ks * 131072 + i4];
    s.x += v.x; s.y += v.y; s.z += v.z; s.w += v.w;
  }
  float4 o;
  o.x = fmaxf(s.x, 0.f); o.y = fmaxf(s.y, 0.f);
  o.z = fmaxf(s.z, 0.f); o.w = fmaxf(s.w, 0.f);
  ((float4*)out)[i4] = o;
}

extern "C" void kernel_launch(void* const* d_in, const int* in_sizes, int n_in,
                              void* d_out, int out_size, void* d_ws, size_t ws_size,
                              hipStream_t stream) {
  const float* value = (const float*)d_in[0];
  const float* key   = (const float*)d_in[1];
  const float* query = (const float*)d_in[2];
  // d_in[3] = mask, unused by the block
  const float* W_ff  = (const float*)d_in[4];
  const float* b_ff  = (const float*)d_in[5];

  float* out  = (float*)d_out;
  float* attn = out + (size_t)2048 * 256;  // outputs: (out, attention) concatenated

  const size_t wb_bytes = (size_t)256 * 16384 * 2;      // 8 MB bf16 W
  const size_t xb_bytes = (size_t)2048 * 64 * 256 * 2;  // 64 MB bf16 x
  const size_t slab     = (size_t)2048 * 256 * 4;       // 2 MB per K-split slab

  // Pick the largest K-split the workspace allows (more resident ff blocks).
  int KS;
  bool use_xb;
  if (ws_size >= wb_bytes + 16 * slab + xb_bytes) {
    KS = 16; use_xb = true;                // 2048 blocks -> 8 blocks/CU
  } else if (ws_size >= wb_bytes + 8 * slab + xb_bytes) {
    KS = 8; use_xb = true;                 // 1024 blocks -> 4 blocks/CU
  } else if (ws_size >= wb_bytes + 4 * slab + xb_bytes) {
    KS = 4; use_xb = true;                 // round-0 footprint
  } else {
    KS = 8; use_xb = false;                // ff recomputes x from attn+query
  }
  const size_t part_bytes = (size_t)KS * slab;

  unsigned short* Wb = (unsigned short*)d_ws;
  float* part = (float*)((char*)d_ws + wb_bytes);
  unsigned short* xb =
      use_xb ? (unsigned short*)((char*)d_ws + wb_bytes + part_bytes) : nullptr;

  w2b_kernel<<<4096, 256, 0, stream>>>(W_ff, Wb);
  attn_kernel<<<2048, 256, 0, stream>>>(value, key, query, attn, xb);
  dim3 gb(32, 4, KS);
  if (use_xb)
    ff_kernel<true><<<gb, 256, 0, stream>>>(xb, nullptr, nullptr, Wb, part, 16384 / KS);
  else
    ff_kernel<false><<<gb, 256, 0, stream>>>(nullptr, attn, query, Wb, part, 16384 / KS);
  relu_kernel<<<512, 256, 0, stream>>>(part, b_ff, out, KS);
}